// Round 1
// baseline (98.068 us; speedup 1.0000x reference)
//
#include <hip/hip_runtime.h>
#include <hip/hip_bf16.h>

#define N_CODECS 1024
#define EPS 1e-8f
#define BLOCKS 256          // 1 block per CU
#define THREADS 512         // 8 waves/CU
#define NCOPIES 8           // global hist copies (stripe contention across XCDs)

// ---------------------------------------------------------------------------
// Fused kernel: per-block LDS histogram -> global atomic merge into 8 striped
// copies -> last-block (ticket) finalize. Replaces the previous 3-kernel
// pipeline (hist -> reduce -> finalize) and its 8 MB of partial traffic.
//
// - Plain cached int4 loads (input is L3-resident after the harness restore;
//   non-temporal loads regressed +6us in a previous round — do not use).
// - 4 independent loads per iteration for memory-level parallelism.
// - LDS atomics only in the hot loop (random bins -> ~4-5 cyc/wave DS op).
// - Merge: each block adds its 1024 LDS bins into copy (blockIdx & 7).
//   Contention per bin per copy = BLOCKS/NCOPIES = 32 serialized RMWs.
// - Ticket: __syncthreads() drains all vmcnt (atomics) before the barrier,
//   thread 0 fences + takes a ticket; the last block re-reads the bins with
//   atomicAdd(bin, 0) — an RMW at the coherence point, safe under per-XCD
//   L2 non-coherence (Guideline 16).
// ---------------------------------------------------------------------------
__global__ void __launch_bounds__(THREADS) fused_hist_perplexity(
        const int* __restrict__ idx,
        unsigned int* __restrict__ ghist,   // [NCOPIES][N_CODECS], pre-zeroed
        unsigned int* __restrict__ done,    // [1], pre-zeroed
        float* __restrict__ out,
        int n4, float invN) {
    __shared__ unsigned int lcounts[N_CODECS];
    #pragma unroll
    for (int i = threadIdx.x; i < N_CODECS; i += THREADS) lcounts[i] = 0u;
    __syncthreads();

    const int4* __restrict__ idx4 = (const int4*)idx;
    const int S = gridDim.x * THREADS;          // 131072 threads
    for (int i = blockIdx.x * THREADS + threadIdx.x; i < n4; i += 4 * S) {
        int i1 = i + S, i2 = i + 2 * S, i3 = i + 3 * S;
        bool h1 = i1 < n4, h2 = i2 < n4, h3 = i3 < n4;
        int4 a = idx4[i];
        int4 b = h1 ? idx4[i1] : make_int4(0, 0, 0, 0);
        int4 c = h2 ? idx4[i2] : make_int4(0, 0, 0, 0);
        int4 d = h3 ? idx4[i3] : make_int4(0, 0, 0, 0);

        atomicAdd(&lcounts[a.x], 1u);
        atomicAdd(&lcounts[a.y], 1u);
        atomicAdd(&lcounts[a.z], 1u);
        atomicAdd(&lcounts[a.w], 1u);
        if (h1) {
            atomicAdd(&lcounts[b.x], 1u);
            atomicAdd(&lcounts[b.y], 1u);
            atomicAdd(&lcounts[b.z], 1u);
            atomicAdd(&lcounts[b.w], 1u);
        }
        if (h2) {
            atomicAdd(&lcounts[c.x], 1u);
            atomicAdd(&lcounts[c.y], 1u);
            atomicAdd(&lcounts[c.z], 1u);
            atomicAdd(&lcounts[c.w], 1u);
        }
        if (h3) {
            atomicAdd(&lcounts[d.x], 1u);
            atomicAdd(&lcounts[d.y], 1u);
            atomicAdd(&lcounts[d.z], 1u);
            atomicAdd(&lcounts[d.w], 1u);
        }
    }
    __syncthreads();

    // Merge into this block's stripe copy (device-scope atomics).
    unsigned int* __restrict__ mycopy = ghist + (size_t)(blockIdx.x & (NCOPIES - 1)) * N_CODECS;
    #pragma unroll
    for (int i = threadIdx.x; i < N_CODECS; i += THREADS)
        atomicAdd(&mycopy[i], lcounts[i]);

    // __syncthreads drains vmcnt -> all of this block's global atomics are
    // globally performed before any thread proceeds.
    __syncthreads();

    __shared__ unsigned int ticket;
    if (threadIdx.x == 0) {
        __threadfence();                     // release before publishing
        ticket = atomicAdd(done, 1u);
    }
    __syncthreads();
    if (ticket != (unsigned int)(gridDim.x - 1)) return;

    // ---- last block: finalize ----
    __threadfence();                         // acquire
    int t = threadIdx.x;
    float term = 0.0f;
    #pragma unroll
    for (int b = t; b < N_CODECS; b += THREADS) {
        unsigned int cnt = 0;
        #pragma unroll
        for (int cpy = 0; cpy < NCOPIES; ++cpy)
            cnt += atomicAdd(&ghist[(size_t)cpy * N_CODECS + b], 0u);  // coherent read
        float p = (float)cnt * invN;
        term += p * logf(p + EPS);
    }

    #pragma unroll
    for (int off = 32; off > 0; off >>= 1) term += __shfl_down(term, off, 64);

    __shared__ float wsum[THREADS / 64];
    int wave = t >> 6;
    int lane = t & 63;
    if (lane == 0) wsum[wave] = term;
    __syncthreads();

    if (wave == 0) {
        float s = (lane < THREADS / 64) ? wsum[lane] : 0.0f;
        #pragma unroll
        for (int off = 4; off > 0; off >>= 1) s += __shfl_down(s, off, 64);
        if (lane == 0) out[0] = expf(-s);
    }
}

extern "C" void kernel_launch(void* const* d_in, const int* in_sizes, int n_in,
                              void* d_out, int out_size, void* d_ws, size_t ws_size,
                              hipStream_t stream) {
    const int* indices = (const int*)d_in[0];
    int n = in_sizes[0];             // 16 * 1048576 = 16,777,216 elements
    float* out = (float*)d_out;

    unsigned int* ghist = (unsigned int*)d_ws;                    // 8 * 4 KB
    unsigned int* done  = ghist + (size_t)NCOPIES * N_CODECS;     // 4 B

    int n4 = n >> 2;

    // Zero the 8 histogram copies + ticket counter (workspace is poisoned
    // by the harness each iteration). 33 KB memset — trivial.
    hipMemsetAsync(d_ws, 0, ((size_t)NCOPIES * N_CODECS + 64) * sizeof(unsigned int), stream);

    fused_hist_perplexity<<<BLOCKS, THREADS, 0, stream>>>(
        indices, ghist, done, out, n4, 1.0f / (float)n);
}